// Round 4
// baseline (351.230 us; speedup 1.0000x reference)
//
#include <hip/hip_runtime.h>
#include <stdint.h>

// ---- problem constants ----
constexpr int NBASES = 32;
constexpr int NKP    = 17;
constexpr int HDIM   = 100, WDIM = 152;
constexpr int HW     = HDIM * WDIM;       // 15200
constexpr int NI     = 64;
constexpr int KF     = 2304;
constexpr int AL     = 2737;
constexpr int ALP    = 2740;              // padded per-instance stride (16B-aligned rows)
// packed reference offsets inside an attns row
constexpr int OB0 = 1088;   // after 32x34 w0
constexpr int OW1 = 1120;
constexpr int OB1 = 2144;
constexpr int OW2 = 2176;
constexpr int OB2 = 2720;
// permuted layout (w0/w1 stored c-major: row per c of 32 o-values; w2 k-major)
constexpr int TW0 = 0;      // [34][32]
constexpr int TB0 = 1088;   // 32
constexpr int TW1 = 1120;   // [32][32]
constexpr int TB1 = 2144;   // 32
constexpr int TW2 = 2176;   // [17][32]
constexpr int TB2 = 2720;   // 17

constexpr int PXB = 512;                     // pixels per block (256 thr x 2 px)
constexpr int NBX = (HW + PXB - 1) / PXB;    // 30
constexpr size_t PART_OFF = (size_t)NI * ALP * 4;   // 701,440 B (8-aligned)

__device__ __forceinline__ int perm(int j) {
    if (j < OB0)      { int o = j / 34, c = j - o * 34; return TW0 + c * 32 + o; }
    else if (j < OW1) return TB0 + (j - OB0);
    else if (j < OB1) { int q = j - OW1; int o = q >> 5, c = q & 31; return TW1 + c * 32 + o; }
    else if (j < OW2) return TB1 + (j - OB1);
    else if (j < OB2) return TW2 + (j - OW2);
    else              return TB2 + (j - OB2);
}

// ================= kernel 0: init permuted attns with bias =================
__global__ __launch_bounds__(256) void init_attn(const float* __restrict__ b,
                                                 float* __restrict__ att_p) {
    int i = blockIdx.x * 256 + threadIdx.x;
    if (i < NI * AL) {
        int n = i / AL, j = i - n * AL;
        att_p[(size_t)n * ALP + perm(j)] = b[j];
    }
}

// ================= kernel 1: attns GEMM (64x2737 = tf @ W^T), permuted output =================
constexpr int JT     = 64;
constexpr int KCH    = 64;
constexpr int KSPLIT = 18;             // KT = 128 -> 774 blocks (~3/CU)
constexpr int KT     = KF / KSPLIT;
constexpr int NJT    = (AL + JT - 1) / JT;  // 43
constexpr int LPAD   = 68;

__global__ __launch_bounds__(256) void gemm_attn(const float* __restrict__ tf,
                                                 const float* __restrict__ W,
                                                 float* __restrict__ att_p) {
    __shared__ __align__(16) float Tl[KCH][LPAD];
    __shared__ __align__(16) float Wl[KCH][LPAD];
    int jb = blockIdx.x % NJT;
    int ks = blockIdx.x / NJT;
    int j0 = jb * JT;
    int k0 = ks * KT;
    int tid = threadIdx.x;
    int tn = tid % 16;
    int tj = tid / 16;
    int lk = tid % 64;
    int lr = tid / 64;
    float acc[4][4] = {};
    for (int kc = 0; kc < KT; kc += KCH) {
        int kbase = k0 + kc;
        #pragma unroll
        for (int i = 0; i < 16; i++) {
            int nn = lr * 16 + i;
            Tl[lk][nn] = tf[(size_t)nn * KF + kbase + lk];
        }
        #pragma unroll
        for (int i = 0; i < 16; i++) {
            int j = j0 + lr * 16 + i;
            Wl[lk][lr * 16 + i] = (j < AL) ? W[(size_t)j * KF + kbase + lk] : 0.0f;
        }
        __syncthreads();
        #pragma unroll 4
        for (int kk = 0; kk < KCH; ++kk) {
            float tv[4], wv[4];
            #pragma unroll
            for (int i = 0; i < 4; i++) tv[i] = Tl[kk][tn * 4 + i];
            #pragma unroll
            for (int i = 0; i < 4; i++) wv[i] = Wl[kk][tj * 4 + i];
            #pragma unroll
            for (int i = 0; i < 4; i++)
                #pragma unroll
                for (int q = 0; q < 4; q++) acc[i][q] += tv[i] * wv[q];
        }
        __syncthreads();
    }
    #pragma unroll
    for (int i = 0; i < 4; i++) {
        int nn = tn * 4 + i;
        #pragma unroll
        for (int q = 0; q < 4; q++) {
            int j = j0 + tj * 4 + q;
            if (j < AL) atomicAdd(&att_p[(size_t)nn * ALP + perm(j)], acc[i][q]);
        }
    }
}

// ================= kernel 2: fused per-pixel head + block argmax =================
// Weights read from global at block-uniform addresses -> scalar loads (SGPR),
// freeing the LDS pipe entirely (only the tiny argmax scratch remains).
__device__ inline unsigned int mono_f32(float f) {
    unsigned int u = __float_as_uint(f);
    return (u & 0x80000000u) ? ~u : (u | 0x80000000u);
}

__global__ __launch_bounds__(256) void pixel_head(const float* __restrict__ bases_full,
                                                  const float* __restrict__ att_p,
                                                  const float* __restrict__ locations,
                                                  const float* __restrict__ soi,
                                                  const int* __restrict__ fpn,
                                                  float* __restrict__ out_logits,
                                                  unsigned long long* __restrict__ partial) {
    __shared__ unsigned long long red[4][NKP];
    int n = blockIdx.y, bx = blockIdx.x, tid = threadIdx.x;
    const float* wn = att_p + (size_t)n * ALP;   // block-uniform base

    int p0 = bx * PXB + tid * 2;
    bool valid = p0 < HW;
    int pc = valid ? p0 : 0;
    int y = pc / WDIM, x = pc - y * WDIM;

    float inv = 1.0f / soi[fpn[n]];
    float lx = locations[2 * n], ly = locations[2 * n + 1];
    float cxa = (lx - (float)(x * 8 + 4)) * inv;
    float cxb = (lx - (float)(x * 8 + 12)) * inv;
    float cyy = (ly - (float)(y * 8 + 4)) * inv;

    // ---- layer 0: h = relu(W0 x + b0), c-outer streaming ----
    float ha[32], hb[32];
    {
        const float4* br  = (const float4*)(wn + TB0);
        const float4* w0r = (const float4*)(wn + TW0);        // c=0 row
        const float4* w1r = (const float4*)(wn + TW0 + 32);   // c=1 row
        #pragma unroll
        for (int g = 0; g < 8; g++) {
            float4 b4 = br[g], wv = w0r[g], wu = w1r[g];
            ha[4*g+0] = b4.x + wv.x * cxa + wu.x * cyy;  hb[4*g+0] = b4.x + wv.x * cxb + wu.x * cyy;
            ha[4*g+1] = b4.y + wv.y * cxa + wu.y * cyy;  hb[4*g+1] = b4.y + wv.y * cxb + wu.y * cyy;
            ha[4*g+2] = b4.z + wv.z * cxa + wu.z * cyy;  hb[4*g+2] = b4.z + wv.z * cxb + wu.z * cyy;
            ha[4*g+3] = b4.w + wv.w * cxa + wu.w * cyy;  hb[4*g+3] = b4.w + wv.w * cxb + wu.w * cyy;
        }
    }
    #pragma unroll 4
    for (int c = 0; c < 32; c++) {
        float2 bv = *(const float2*)&bases_full[(size_t)c * HW + pc];
        const float4* wr = (const float4*)(wn + TW0 + (c + 2) * 32);
        #pragma unroll
        for (int g = 0; g < 8; g++) {
            float4 wv = wr[g];
            ha[4*g+0] += wv.x * bv.x;  hb[4*g+0] += wv.x * bv.y;
            ha[4*g+1] += wv.y * bv.x;  hb[4*g+1] += wv.y * bv.y;
            ha[4*g+2] += wv.z * bv.x;  hb[4*g+2] += wv.z * bv.y;
            ha[4*g+3] += wv.w * bv.x;  hb[4*g+3] += wv.w * bv.y;
        }
    }
    #pragma unroll
    for (int o = 0; o < 32; o++) {
        ha[o] = fmaxf(ha[o], 0.0f);
        hb[o] = fmaxf(hb[o], 0.0f);
    }

    // ---- layer 1: g = relu(W1 h + b1), c-outer streaming ----
    float ga[32], gb[32];
    {
        const float4* br = (const float4*)(wn + TB1);
        #pragma unroll
        for (int g = 0; g < 8; g++) {
            float4 b4 = br[g];
            ga[4*g+0] = b4.x; ga[4*g+1] = b4.y; ga[4*g+2] = b4.z; ga[4*g+3] = b4.w;
        }
        #pragma unroll
        for (int o = 0; o < 32; o++) gb[o] = ga[o];
    }
    #pragma unroll 4
    for (int c = 0; c < 32; c++) {
        float xa = ha[c], xb = hb[c];
        const float4* wr = (const float4*)(wn + TW1 + c * 32);
        #pragma unroll
        for (int g = 0; g < 8; g++) {
            float4 wv = wr[g];
            ga[4*g+0] += wv.x * xa;  gb[4*g+0] += wv.x * xb;
            ga[4*g+1] += wv.y * xa;  gb[4*g+1] += wv.y * xb;
            ga[4*g+2] += wv.z * xa;  gb[4*g+2] += wv.z * xb;
            ga[4*g+3] += wv.w * xa;  gb[4*g+3] += wv.w * xb;
        }
    }
    #pragma unroll
    for (int o = 0; o < 32; o++) {
        ga[o] = fmaxf(ga[o], 0.0f);
        gb[o] = fmaxf(gb[o], 0.0f);
    }

    // ---- layer 2 (17 outputs): store logits + fused per-k argmax ----
    size_t obase = (size_t)n * NKP * HW;
    int wid = tid >> 6, lane = tid & 63;
    #pragma unroll
    for (int k = 0; k < NKP; k++) {
        const float4* wr = (const float4*)(wn + TW2 + k * 32);
        float sa = wn[TB2 + k], sb = sa;
        #pragma unroll
        for (int g = 0; g < 8; g++) {
            float4 wv = wr[g];
            sa += wv.x * ga[4*g+0] + wv.y * ga[4*g+1] + wv.z * ga[4*g+2] + wv.w * ga[4*g+3];
            sb += wv.x * gb[4*g+0] + wv.y * gb[4*g+1] + wv.z * gb[4*g+2] + wv.w * gb[4*g+3];
        }
        unsigned long long pk = 0;
        if (valid) {
            *(float2*)&out_logits[obase + (size_t)k * HW + p0] = make_float2(sa, sb);
            float bv = sa; int bp = p0;
            if (sb > sa) { bv = sb; bp = p0 + 1; }   // tie -> smaller index (numpy)
            pk = ((unsigned long long)mono_f32(bv) << 32) |
                 (unsigned long long)(0xFFFFFFFFu - (unsigned)bp);
        }
        #pragma unroll
        for (int off = 32; off > 0; off >>= 1) {
            unsigned long long o = __shfl_down(pk, off);
            if (o > pk) pk = o;
        }
        if (lane == 0) red[wid][k] = pk;
    }
    __syncthreads();
    if (tid < NKP) {
        unsigned long long m = red[0][tid];
        #pragma unroll
        for (int ww = 1; ww < 4; ww++)
            if (red[ww][tid] > m) m = red[ww][tid];
        partial[((size_t)n * NKP + tid) * NBX + bx] = m;
    }
}

// ================= kernel 3: final argmax reduce + keypoint =================
__global__ __launch_bounds__(64) void kp_final(const unsigned long long* __restrict__ partial,
                                               const float* __restrict__ bases_full,
                                               float* __restrict__ kp_out) {
    int b = blockIdx.x;
    int n = b / NKP, k = b % NKP;
    int lane = threadIdx.x;
    unsigned long long v = (lane < NBX) ? partial[((size_t)n * NKP + k) * NBX + lane] : 0ull;
    #pragma unroll
    for (int off = 32; off > 0; off >>= 1) {
        unsigned long long o = __shfl_down(v, off);
        if (o > v) v = o;
    }
    if (lane == 0) {
        int p = (int)(0xFFFFFFFFu - (unsigned)(v & 0xFFFFFFFFull));
        int yy = p / WDIM;
        int xx = p - yy * WDIM;
        float kx = bases_full[(size_t)(NBASES + 2 * k) * HW + p] + (float)(xx * 8 + 4);
        float ky = bases_full[(size_t)(NBASES + 2 * k + 1) * HW + p] + (float)(yy * 8 + 4);
        kp_out[((size_t)n * NKP + k) * 2 + 0] = kx;
        kp_out[((size_t)n * NKP + k) * 2 + 1] = ky;
    }
}

extern "C" void kernel_launch(void* const* d_in, const int* in_sizes, int n_in,
                              void* d_out, int out_size, void* d_ws, size_t ws_size,
                              hipStream_t stream) {
    const float* bases_full = (const float*)d_in[0];
    const float* top_feats  = (const float*)d_in[1];
    const float* locations  = (const float*)d_in[2];
    const float* atten_W    = (const float*)d_in[3];
    const float* atten_b    = (const float*)d_in[4];
    const float* soi        = (const float*)d_in[5];
    const int*   fpn        = (const int*)d_in[6];
    float* out   = (float*)d_out;
    float* att_p = (float*)d_ws;
    unsigned long long* partial = (unsigned long long*)((char*)d_ws + PART_OFF);

    init_attn<<<(NI * AL + 255) / 256, 256, 0, stream>>>(atten_b, att_p);
    gemm_attn<<<NJT * KSPLIT, 256, 0, stream>>>(top_feats, atten_W, att_p);

    dim3 g2(NBX, NI);   // 30 x 64
    pixel_head<<<g2, 256, 0, stream>>>(bases_full, att_p, locations, soi, fpn, out, partial);

    float* kp_out = out + (size_t)NI * NKP * HW;
    kp_final<<<NI * NKP, 64, 0, stream>>>(partial, bases_full, kp_out);
}

// Round 5
// 226.224 us; speedup vs baseline: 1.5526x; 1.5526x over previous
//
#include <hip/hip_runtime.h>
#include <stdint.h>

// ---- problem constants ----
constexpr int NBASES = 32;
constexpr int NKP    = 17;
constexpr int HDIM   = 100, WDIM = 152;
constexpr int HW     = HDIM * WDIM;       // 15200
constexpr int NI     = 64;
constexpr int KF     = 2304;
constexpr int AL     = 2737;
constexpr int ALP    = 2740;              // padded per-instance stride (16B-aligned rows)
// packed reference offsets inside an attns row
constexpr int OB0 = 1088;
constexpr int OW1 = 1120;
constexpr int OB1 = 2144;
constexpr int OW2 = 2176;
constexpr int OB2 = 2720;
// permuted layout (w0/w1 c-major; w2 k-major)
constexpr int TW0 = 0;      // [34][32]
constexpr int TB0 = 1088;   // 32
constexpr int TW1 = 1120;   // [32][32]
constexpr int TB1 = 2144;   // 32
constexpr int TW2 = 2176;   // [17][32]
constexpr int TB2 = 2720;   // 17

constexpr int PXB = 512;                     // pixels per block (256 thr x 2 px)
constexpr int NBX = (HW + PXB - 1) / PXB;    // 30

// gemm tiling
constexpr int JT     = 64;
constexpr int KCH    = 64;
constexpr int KSPLIT = 12;             // KT = 192 -> 516 blocks (~2/CU)
constexpr int KT     = KF / KSPLIT;
constexpr int NJT    = (AL + JT - 1) / JT;  // 43
constexpr int JTOT   = NJT * JT;            // 2752
constexpr int LPAD   = 68;

// ws layout (bytes)
constexpr size_t ATT_OFF   = 0;                                  // NI*ALP*4   = 701,440
constexpr size_t ARGP_OFF  = (size_t)NI * ALP * 4;               // 701,440
constexpr size_t GEMMP_OFF = ARGP_OFF + (size_t)NI * NKP * NBX * 8;  // 962,560
// gemm partial size: KSPLIT*NI*JTOT*4 = 8,454,144 -> total ~9.4 MB

__device__ __forceinline__ int perm(int j) {
    if (j < OB0)      { int o = j / 34, c = j - o * 34; return TW0 + c * 32 + o; }
    else if (j < OW1) return TB0 + (j - OB0);
    else if (j < OB1) { int q = j - OW1; int o = q >> 5, c = q & 31; return TW1 + c * 32 + o; }
    else if (j < OW2) return TB1 + (j - OB1);
    else if (j < OB2) return TW2 + (j - OW2);
    else              return TB2 + (j - OB2);
}

// ========== kernel 1: attns GEMM partials (no atomics) ==========
__global__ __launch_bounds__(256) void gemm_attn(const float* __restrict__ tf,
                                                 const float* __restrict__ W,
                                                 float* __restrict__ partial) {
    __shared__ __align__(16) float Tl[KCH][LPAD];
    __shared__ __align__(16) float Wl[KCH][LPAD];
    int jb = blockIdx.x % NJT;
    int ks = blockIdx.x / NJT;
    int j0 = jb * JT;
    int k0 = ks * KT;
    int tid = threadIdx.x;
    int tn = tid % 16;
    int tj = tid / 16;
    int lk = tid % 64;
    int lr = tid / 64;
    float acc[4][4] = {};
    for (int kc = 0; kc < KT; kc += KCH) {
        int kbase = k0 + kc;
        #pragma unroll
        for (int i = 0; i < 16; i++) {
            int nn = lr * 16 + i;
            Tl[lk][nn] = tf[(size_t)nn * KF + kbase + lk];
        }
        #pragma unroll
        for (int i = 0; i < 16; i++) {
            int j = j0 + lr * 16 + i;
            Wl[lk][lr * 16 + i] = (j < AL) ? W[(size_t)j * KF + kbase + lk] : 0.0f;
        }
        __syncthreads();
        #pragma unroll 4
        for (int kk = 0; kk < KCH; ++kk) {
            float tv[4], wv[4];
            #pragma unroll
            for (int i = 0; i < 4; i++) tv[i] = Tl[kk][tn * 4 + i];
            #pragma unroll
            for (int i = 0; i < 4; i++) wv[i] = Wl[kk][tj * 4 + i];
            #pragma unroll
            for (int i = 0; i < 4; i++)
                #pragma unroll
                for (int q = 0; q < 4; q++) acc[i][q] += tv[i] * wv[q];
        }
        __syncthreads();
    }
    // plain stores to disjoint per-ks partials (float4, 16B-aligned)
    size_t pbase = (size_t)(ks * NI) * JTOT;
    #pragma unroll
    for (int i = 0; i < 4; i++) {
        int nn = tn * 4 + i;
        int j = j0 + tj * 4;
        float4 st = make_float4(acc[i][0], acc[i][1], acc[i][2], acc[i][3]);
        *(float4*)&partial[pbase + (size_t)nn * JTOT + j] = st;
    }
}

// ========== kernel 2: reduce partials + bias -> permuted att_p ==========
__global__ __launch_bounds__(256) void reduce_attn(const float* __restrict__ partial,
                                                   const float* __restrict__ b,
                                                   float* __restrict__ att_p) {
    int n = blockIdx.y;
    int j = blockIdx.x * 256 + threadIdx.x;
    if (j >= AL) return;
    float s = b[j];
    #pragma unroll
    for (int ks = 0; ks < KSPLIT; ks++)
        s += partial[(size_t)(ks * NI + n) * JTOT + j];
    att_p[(size_t)n * ALP + perm(j)] = s;
}

// ========== kernel 3: fused per-pixel head + block argmax ==========
// LDS indices for the staged regions [0,1120) and [2144,2740):
constexpr int LB0 = 1088;          // bias0 (same as TB0)
constexpr int LB1 = 1120;          // = 2144 - 1024
constexpr int LW2 = 1152;          // = 2176 - 1024
constexpr int LB2 = 1696;          // = 2720 - 1024
constexpr int LTOT = 1716;

__device__ inline unsigned int mono_f32(float f) {
    unsigned int u = __float_as_uint(f);
    return (u & 0x80000000u) ? ~u : (u | 0x80000000u);
}

__global__ __launch_bounds__(256) void pixel_head(const float* __restrict__ bases_full,
                                                  const float* __restrict__ att_p,
                                                  const float* __restrict__ locations,
                                                  const float* __restrict__ soi,
                                                  const int* __restrict__ fpn,
                                                  float* __restrict__ out_logits,
                                                  unsigned long long* __restrict__ partial) {
    __shared__ __align__(16) float w[LTOT];
    __shared__ unsigned long long red[4][NKP];
    int n = blockIdx.y, bx = blockIdx.x, tid = threadIdx.x;
    const float* wn = att_p + (size_t)n * ALP;   // block-uniform base

    {   // contiguous float4 staging: [0,1120) -> w[0,1120); [2144,2740) -> w[1120,1716)
        const float4* s4 = (const float4*)wn;
        float4* d4 = (float4*)w;
        for (int i = tid; i < 280; i += 256) d4[i] = s4[i];
        if (tid < 149) d4[280 + tid] = s4[536 + tid];
    }
    __syncthreads();

    int p0 = bx * PXB + tid * 2;
    bool valid = p0 < HW;
    int pc = valid ? p0 : 0;
    int y = pc / WDIM, x = pc - y * WDIM;

    float inv = 1.0f / soi[fpn[n]];
    float lx = locations[2 * n], ly = locations[2 * n + 1];
    float cxa = (lx - (float)(x * 8 + 4)) * inv;
    float cxb = (lx - (float)(x * 8 + 12)) * inv;
    float cyy = (ly - (float)(y * 8 + 4)) * inv;

    // ---- layer 0 (LDS weights): h = relu(W0 x + b0), c-outer streaming ----
    float ha[32], hb[32];
    {
        const float4* br  = (const float4*)&w[LB0];
        const float4* w0r = (const float4*)&w[TW0];
        const float4* w1r = (const float4*)&w[TW0 + 32];
        #pragma unroll
        for (int g = 0; g < 8; g++) {
            float4 b4 = br[g], wv = w0r[g], wu = w1r[g];
            ha[4*g+0] = b4.x + wv.x * cxa + wu.x * cyy;  hb[4*g+0] = b4.x + wv.x * cxb + wu.x * cyy;
            ha[4*g+1] = b4.y + wv.y * cxa + wu.y * cyy;  hb[4*g+1] = b4.y + wv.y * cxb + wu.y * cyy;
            ha[4*g+2] = b4.z + wv.z * cxa + wu.z * cyy;  hb[4*g+2] = b4.z + wv.z * cxb + wu.z * cyy;
            ha[4*g+3] = b4.w + wv.w * cxa + wu.w * cyy;  hb[4*g+3] = b4.w + wv.w * cxb + wu.w * cyy;
        }
    }
    #pragma unroll 4
    for (int c = 0; c < 32; c++) {
        float2 bv = *(const float2*)&bases_full[(size_t)c * HW + pc];
        const float4* wr = (const float4*)&w[TW0 + (c + 2) * 32];
        #pragma unroll
        for (int g = 0; g < 8; g++) {
            float4 wv = wr[g];
            ha[4*g+0] += wv.x * bv.x;  hb[4*g+0] += wv.x * bv.y;
            ha[4*g+1] += wv.y * bv.x;  hb[4*g+1] += wv.y * bv.y;
            ha[4*g+2] += wv.z * bv.x;  hb[4*g+2] += wv.z * bv.y;
            ha[4*g+3] += wv.w * bv.x;  hb[4*g+3] += wv.w * bv.y;
        }
    }
    #pragma unroll
    for (int o = 0; o < 32; o++) {
        ha[o] = fmaxf(ha[o], 0.0f);
        hb[o] = fmaxf(hb[o], 0.0f);
    }

    // ---- layer 1 (GLOBAL weights, block-uniform -> L1-resident broadcast) ----
    float ga[32], gb[32];
    {
        const float4* br = (const float4*)&w[LB1];
        #pragma unroll
        for (int g = 0; g < 8; g++) {
            float4 b4 = br[g];
            ga[4*g+0] = b4.x; ga[4*g+1] = b4.y; ga[4*g+2] = b4.z; ga[4*g+3] = b4.w;
        }
        #pragma unroll
        for (int o = 0; o < 32; o++) gb[o] = ga[o];
    }
    #pragma unroll 4
    for (int c = 0; c < 32; c++) {
        float xa = ha[c], xb = hb[c];
        const float4* wr = (const float4*)(wn + TW1 + c * 32);   // global, uniform
        #pragma unroll
        for (int g = 0; g < 8; g++) {
            float4 wv = wr[g];
            ga[4*g+0] += wv.x * xa;  gb[4*g+0] += wv.x * xb;
            ga[4*g+1] += wv.y * xa;  gb[4*g+1] += wv.y * xb;
            ga[4*g+2] += wv.z * xa;  gb[4*g+2] += wv.z * xb;
            ga[4*g+3] += wv.w * xa;  gb[4*g+3] += wv.w * xb;
        }
    }
    #pragma unroll
    for (int o = 0; o < 32; o++) {
        ga[o] = fmaxf(ga[o], 0.0f);
        gb[o] = fmaxf(gb[o], 0.0f);
    }

    // ---- layer 2 (LDS weights): store logits + fused per-k argmax ----
    size_t obase = (size_t)n * NKP * HW;
    int wid = tid >> 6, lane = tid & 63;
    #pragma unroll
    for (int k = 0; k < NKP; k++) {
        const float4* wr = (const float4*)&w[LW2 + k * 32];
        float sa = w[LB2 + k], sb = sa;
        #pragma unroll
        for (int g = 0; g < 8; g++) {
            float4 wv = wr[g];
            sa += wv.x * ga[4*g+0] + wv.y * ga[4*g+1] + wv.z * ga[4*g+2] + wv.w * ga[4*g+3];
            sb += wv.x * gb[4*g+0] + wv.y * gb[4*g+1] + wv.z * gb[4*g+2] + wv.w * gb[4*g+3];
        }
        unsigned long long pk = 0;
        if (valid) {
            *(float2*)&out_logits[obase + (size_t)k * HW + p0] = make_float2(sa, sb);
            float bv = sa; int bp = p0;
            if (sb > sa) { bv = sb; bp = p0 + 1; }   // tie -> smaller index (numpy)
            pk = ((unsigned long long)mono_f32(bv) << 32) |
                 (unsigned long long)(0xFFFFFFFFu - (unsigned)bp);
        }
        #pragma unroll
        for (int off = 32; off > 0; off >>= 1) {
            unsigned long long o = __shfl_down(pk, off);
            if (o > pk) pk = o;
        }
        if (lane == 0) red[wid][k] = pk;
    }
    __syncthreads();
    if (tid < NKP) {
        unsigned long long m = red[0][tid];
        #pragma unroll
        for (int ww = 1; ww < 4; ww++)
            if (red[ww][tid] > m) m = red[ww][tid];
        partial[((size_t)n * NKP + tid) * NBX + bx] = m;
    }
}

// ========== kernel 4: final argmax reduce + keypoint ==========
__global__ __launch_bounds__(64) void kp_final(const unsigned long long* __restrict__ partial,
                                               const float* __restrict__ bases_full,
                                               float* __restrict__ kp_out) {
    int b = blockIdx.x;
    int n = b / NKP, k = b % NKP;
    int lane = threadIdx.x;
    unsigned long long v = (lane < NBX) ? partial[((size_t)n * NKP + k) * NBX + lane] : 0ull;
    #pragma unroll
    for (int off = 32; off > 0; off >>= 1) {
        unsigned long long o = __shfl_down(v, off);
        if (o > v) v = o;
    }
    if (lane == 0) {
        int p = (int)(0xFFFFFFFFu - (unsigned)(v & 0xFFFFFFFFull));
        int yy = p / WDIM;
        int xx = p - yy * WDIM;
        float kx = bases_full[(size_t)(NBASES + 2 * k) * HW + p] + (float)(xx * 8 + 4);
        float ky = bases_full[(size_t)(NBASES + 2 * k + 1) * HW + p] + (float)(yy * 8 + 4);
        kp_out[((size_t)n * NKP + k) * 2 + 0] = kx;
        kp_out[((size_t)n * NKP + k) * 2 + 1] = ky;
    }
}

extern "C" void kernel_launch(void* const* d_in, const int* in_sizes, int n_in,
                              void* d_out, int out_size, void* d_ws, size_t ws_size,
                              hipStream_t stream) {
    const float* bases_full = (const float*)d_in[0];
    const float* top_feats  = (const float*)d_in[1];
    const float* locations  = (const float*)d_in[2];
    const float* atten_W    = (const float*)d_in[3];
    const float* atten_b    = (const float*)d_in[4];
    const float* soi        = (const float*)d_in[5];
    const int*   fpn        = (const int*)d_in[6];
    float* out   = (float*)d_out;
    float* att_p = (float*)((char*)d_ws + ATT_OFF);
    unsigned long long* argp = (unsigned long long*)((char*)d_ws + ARGP_OFF);
    float* gemmp = (float*)((char*)d_ws + GEMMP_OFF);

    gemm_attn<<<NJT * KSPLIT, 256, 0, stream>>>(top_feats, atten_W, gemmp);

    dim3 gr((AL + 255) / 256, NI);   // 11 x 64
    reduce_attn<<<gr, 256, 0, stream>>>(gemmp, atten_b, att_p);

    dim3 g2(NBX, NI);   // 30 x 64
    pixel_head<<<g2, 256, 0, stream>>>(bases_full, att_p, locations, soi, fpn, out, argp);

    float* kp_out = out + (size_t)NI * NKP * HW;
    kp_final<<<NI * NKP, 64, 0, stream>>>(argp, bases_full, kp_out);
}